// Round 5
// baseline (266.300 us; speedup 1.0000x reference)
//
#include <hip/hip_runtime.h>
#include <hip/hip_bf16.h>

#define B_    16
#define C_    512
#define S_    1024      // H*W
#define NGRP  32
#define CPG   16

typedef __attribute__((ext_vector_type(8))) short  short8;
typedef __attribute__((ext_vector_type(4))) short  short4v;
typedef __attribute__((ext_vector_type(4))) float  floatx4;

__device__ __forceinline__ unsigned short f2bf(float f) {
    __hip_bfloat16 h = __float2bfloat16(f);
    unsigned short u;
    __builtin_memcpy(&u, &h, 2);
    return u;
}

// ---------------------------------------------------------------------------
// Fused GroupNorm (+transpose to xnT[b][s][c] bf16), single pass over x.
// ---------------------------------------------------------------------------
__global__ __launch_bounds__(256)
void gn_fused_kernel(const float* __restrict__ x, const float* __restrict__ w,
                     const float* __restrict__ bias, __hip_bfloat16* __restrict__ xnT) {
    int bg = blockIdx.x;
    int b = bg >> 5, g = bg & 31;
    const float4* xp = (const float4*)(x + (size_t)bg * (CPG * S_));
    int tid = threadIdx.x;

    float4 vv[16];
    float s = 0.f, ss = 0.f;
#pragma unroll
    for (int r = 0; r < 16; ++r) {
        float4 v = xp[r * 256 + tid];
        vv[r] = v;
        s  += v.x + v.y + v.z + v.w;
        ss += v.x*v.x + v.y*v.y + v.z*v.z + v.w*v.w;
    }
    for (int off = 32; off > 0; off >>= 1) {
        s  += __shfl_down(s, off);
        ss += __shfl_down(ss, off);
    }
    __shared__ float red[2][4];
    __shared__ float msh[2];
    int wid = tid >> 6, lane = tid & 63;
    if (lane == 0) { red[0][wid] = s; red[1][wid] = ss; }
    __syncthreads();
    if (tid == 0) {
        float a = 0.f, c = 0.f;
        for (int i = 0; i < 4; ++i) { a += red[0][i]; c += red[1][i]; }
        float mean = a / (float)(CPG * S_);
        float var  = c / (float)(CPG * S_) - mean * mean;
        msh[0] = mean;
        msh[1] = rsqrtf(var + 1e-5f);
    }
    __syncthreads();
    float mean = msh[0], inv = msh[1];

    float sc[16], sh[16];
#pragma unroll
    for (int c = 0; c < 16; ++c) {
        float wc = w[g * 16 + c];
        sc[c] = inv * wc;
        sh[c] = bias[g * 16 + c] - mean * inv * wc;
    }

#pragma unroll
    for (int kk = 0; kk < 4; ++kk) {
        unsigned short outp[16];
#pragma unroll
        for (int c = 0; c < 16; ++c) {
            float v = (kk == 0) ? vv[c].x : (kk == 1) ? vv[c].y : (kk == 2) ? vv[c].z : vv[c].w;
            outp[c] = f2bf(v * sc[c] + sh[c]);
        }
        int srow = 4 * tid + kk;
        unsigned short* dst = (unsigned short*)xnT + ((size_t)(b * S_ + srow) * C_ + g * 16);
        *(short8*)dst       = *(short8*)outp;
        *(short8*)(dst + 8) = *(short8*)(outp + 8);
    }
}

// ---------------------------------------------------------------------------
// Prep: weight transposes->bf16, wp convert, bias matvecs.
// blocks 0..191: 64x64 transpose tiles (mat0: WkT<-Wk, mat1: WqT<-Wq, mat2: WvT<-Wv)
// blocks 192..255: wp fp32->bf16
// block 256: bqWk[j] = sum_o qkv_b[o] * Wk[o][j]
// block 257: biasvp[c] = sum_k Wp[c][k] * qkv_b[1024+k]
// ---------------------------------------------------------------------------
__global__ __launch_bounds__(256)
void prep_kernel(const float* __restrict__ qkv_w, const float* __restrict__ proj_w,
                 const float* __restrict__ qkv_b,
                 unsigned short* __restrict__ bufX,   // [WkT | wp_bf]
                 unsigned short* __restrict__ bufY,   // [WqT | WvT]
                 float* __restrict__ bqWk, float* __restrict__ biasvp)
{
    int blk = blockIdx.x;
    int tid = threadIdx.x;
    if (blk < 192) {
        __shared__ float T[64][65];
        int mat = blk >> 6, tile = blk & 63;
        int r0 = (tile >> 3) * 64, c0 = (tile & 7) * 64;  // dst[r0+i][c0+j] = src[c0+j][r0+i]
        const float* src; unsigned short* dst;
        if (mat == 0)      { src = qkv_w + 512 * 512;  dst = bufX; }
        else if (mat == 1) { src = qkv_w;              dst = bufY; }
        else               { src = qkv_w + 1024 * 512; dst = bufY + 262144; }
#pragma unroll
        for (int rr = 0; rr < 4; ++rr) {
            int sr = rr * 16 + (tid >> 4);     // src row offset within tile (the j dim)
            int sc = (tid & 15) * 4;           // src col offset (the i dim)
            float4 v = *(const float4*)(src + (size_t)(c0 + sr) * 512 + r0 + sc);
            T[sc][sr] = v.x; T[sc + 1][sr] = v.y; T[sc + 2][sr] = v.z; T[sc + 3][sr] = v.w;
        }
        __syncthreads();
#pragma unroll
        for (int rr = 0; rr < 4; ++rr) {
            int dr = rr * 16 + (tid >> 4);
            int dc = (tid & 15) * 4;
            short4v o;
            o[0] = (short)f2bf(T[dr][dc]);     o[1] = (short)f2bf(T[dr][dc + 1]);
            o[2] = (short)f2bf(T[dr][dc + 2]); o[3] = (short)f2bf(T[dr][dc + 3]);
            *(short4v*)(dst + (size_t)(r0 + dr) * 512 + c0 + dc) = o;
        }
    } else if (blk < 256) {
        unsigned short* wp = bufX + 262144;
#pragma unroll
        for (int t = 0; t < 4; ++t) {
            int i = (blk - 192) * 4096 + t * 1024 + tid * 4;
            float4 v = *(const float4*)(proj_w + i);
            short4v o;
            o[0] = (short)f2bf(v.x); o[1] = (short)f2bf(v.y);
            o[2] = (short)f2bf(v.z); o[3] = (short)f2bf(v.w);
            *(short4v*)(wp + i) = o;
        }
    } else if (blk == 256) {
        for (int j = tid; j < 512; j += 256) {
            float s = 0.f;
#pragma unroll 8
            for (int o = 0; o < 512; ++o)
                s += qkv_b[o] * qkv_w[(size_t)(512 + o) * 512 + j];
            bqWk[j] = s;
        }
    } else {
        int w = tid >> 6, lane = tid & 63;
        for (int cc = 0; cc < 128; ++cc) {
            int c = w * 128 + cc;
            float s = 0.f;
#pragma unroll
            for (int t = 0; t < 8; ++t)
                s += proj_w[(size_t)c * 512 + t * 64 + lane] * qkv_b[1024 + t * 64 + lane];
            for (int off = 32; off > 0; off >>= 1) s += __shfl_down(s, off);
            if (lane == 0) biasvp[c] = s;
        }
    }
}

// ---------------------------------------------------------------------------
// Uniform NT bf16 MFMA GEMM, BK=64 (two lane-linear 32-k sub-stages per
// barrier-pair, 32 MFMA between barriers). C[m][n] = alpha*sum A[m][k]B[n][k].
// BIAS_MODE: 0 none, 1 bias[m], 2 bias[n]. KTOT compile-time for full unroll.
// ---------------------------------------------------------------------------
template<int BIAS_MODE, bool OUT_BF16, bool RESID, bool SWIZ, int KTOT>
__global__ __launch_bounds__(256)
void mfma_gemm(const unsigned short* __restrict__ A, const unsigned short* __restrict__ Bm,
               const float* __restrict__ bias, const float* __restrict__ resid,
               void* __restrict__ Yv,
               int lda, int ldb, int ldy,
               size_t sA, size_t sB, size_t sY, size_t sR, float alpha,
               int ntsh, int nxsh)
{
    __shared__ unsigned short As[2 * 128 * 32];
    __shared__ unsigned short Bs[2 * 128 * 32];
    int bx, by, bz;
    if (SWIZ) {
        int lin = blockIdx.x;
        int xcd = lin & 7, sup = lin >> 3;
        bz = xcd + ((sup >> ntsh) << 3);
        int tile = sup & ((1 << ntsh) - 1);
        bx = tile & ((1 << nxsh) - 1);
        by = tile >> nxsh;
    } else { bx = blockIdx.x; by = blockIdx.y; bz = blockIdx.z; }

    const unsigned short* Ab = A  + (size_t)bz * sA;
    const unsigned short* Bb = Bm + (size_t)bz * sB;
    const int tid = threadIdx.x, wave = tid >> 6, lane = tid & 63;
    const int m0 = by * 128, n0 = bx * 128;
    const int wr = wave >> 1, wc = wave & 1, lr = lane & 15, kq = lane >> 4;
    const int row0 = tid >> 2, kc0 = (tid & 3) << 3;

    floatx4 acc[4][4] = {};

    for (int k0 = 0; k0 < KTOT; k0 += 64) {
        __syncthreads();
#pragma unroll
        for (int kk = 0; kk < 2; ++kk) {
#pragma unroll
            for (int r = 0; r < 2; ++r) {
                const unsigned short* ga = Ab + (size_t)(m0 + r * 64 + row0) * lda + k0 + kk * 32 + kc0;
                __builtin_amdgcn_global_load_lds(
                    (const __attribute__((address_space(1))) void*)ga,
                    (__attribute__((address_space(3))) void*)(As + kk * 4096 + (r * 256 + wave * 64) * 8),
                    16, 0, 0);
                const unsigned short* gb = Bb + (size_t)(n0 + r * 64 + row0) * ldb + k0 + kk * 32 + kc0;
                __builtin_amdgcn_global_load_lds(
                    (const __attribute__((address_space(1))) void*)gb,
                    (__attribute__((address_space(3))) void*)(Bs + kk * 4096 + (r * 256 + wave * 64) * 8),
                    16, 0, 0);
            }
        }
        __syncthreads();

#pragma unroll
        for (int kk = 0; kk < 2; ++kk) {
            short8 af[4], bfr[4];
#pragma unroll
            for (int i = 0; i < 4; ++i)
                af[i] = *(const short8*)&As[kk * 4096 + (wr * 64 + i * 16 + lr) * 32 + kq * 8];
#pragma unroll
            for (int j = 0; j < 4; ++j)
                bfr[j] = *(const short8*)&Bs[kk * 4096 + (wc * 64 + j * 16 + lr) * 32 + kq * 8];
#pragma unroll
            for (int i = 0; i < 4; ++i)
#pragma unroll
                for (int j = 0; j < 4; ++j)
                    acc[i][j] = __builtin_amdgcn_mfma_f32_16x16x32_bf16(af[i], bfr[j], acc[i][j], 0, 0, 0);
        }
    }

    const size_t ybase = (size_t)bz * sY;
    const size_t rbase = (size_t)bz * sR;
#pragma unroll
    for (int i = 0; i < 4; ++i) {
#pragma unroll
        for (int r = 0; r < 4; ++r) {
            int m = m0 + wr * 64 + i * 16 + kq * 4 + r;
            float bm = (BIAS_MODE == 1) ? bias[m] : 0.f;
#pragma unroll
            for (int j = 0; j < 4; ++j) {
                int n = n0 + wc * 64 + j * 16 + lr;
                float vv = acc[i][j][r] * alpha + bm;
                if (BIAS_MODE == 2) vv += bias[n];
                if (RESID) vv += resid[rbase + (size_t)m * ldy + n];
                if (OUT_BF16)
                    ((__hip_bfloat16*)Yv)[ybase + (size_t)m * ldy + n] = __float2bfloat16(vv);
                else
                    ((float*)Yv)[ybase + (size_t)m * ldy + n] = vv;
            }
        }
    }
}

// ---------------------------------------------------------------------------
// Scores^T GEMM (BK=64) + fused 32-key-chunk softmax + LDS transpose.
// S^T[key][sq] = sum_c xnT[key][c] * u[sq][c]; sq-only logit terms cancel in
// the 32-chunk softmax. P written [sq][key] via padded-LDS transpose.
// XCD-swizzled 1-D grid (1024 blocks).
// ---------------------------------------------------------------------------
__global__ __launch_bounds__(256)
void scores_softmax_kernel(const unsigned short* __restrict__ A,   // xnT (keys)
                           const unsigned short* __restrict__ Bm,  // u (queries)
                           unsigned short* __restrict__ P)
{
    __shared__ unsigned short smem[128 * 136];   // 34816 B; staging then P-tile
    unsigned short* As = smem;                    // 2*128*32 = 8192
    unsigned short* Bs = smem + 8192;

    int lin = blockIdx.x;
    int xcd = lin & 7, sup = lin >> 3;
    int bz = xcd + ((sup >> 6) << 3);
    int tile = sup & 63;
    int bx = tile & 7, by = tile >> 3;

    const size_t sAB = (size_t)S_ * 512;
    const unsigned short* Ab = A  + (size_t)bz * sAB;
    const unsigned short* Bb = Bm + (size_t)bz * sAB;
    const int tid = threadIdx.x, wave = tid >> 6, lane = tid & 63;
    const int m0 = by * 128, n0 = bx * 128;     // m = key, n = sq
    const int wr = wave >> 1, wc = wave & 1, lr = lane & 15, kq = lane >> 4;
    const int row0 = tid >> 2, kc0 = (tid & 3) << 3;

    floatx4 acc[4][4] = {};

    for (int k0 = 0; k0 < 512; k0 += 64) {
        __syncthreads();
#pragma unroll
        for (int kk = 0; kk < 2; ++kk) {
#pragma unroll
            for (int r = 0; r < 2; ++r) {
                const unsigned short* ga = Ab + (size_t)(m0 + r * 64 + row0) * 512 + k0 + kk * 32 + kc0;
                __builtin_amdgcn_global_load_lds(
                    (const __attribute__((address_space(1))) void*)ga,
                    (__attribute__((address_space(3))) void*)(As + kk * 4096 + (r * 256 + wave * 64) * 8),
                    16, 0, 0);
                const unsigned short* gb = Bb + (size_t)(n0 + r * 64 + row0) * 512 + k0 + kk * 32 + kc0;
                __builtin_amdgcn_global_load_lds(
                    (const __attribute__((address_space(1))) void*)gb,
                    (__attribute__((address_space(3))) void*)(Bs + kk * 4096 + (r * 256 + wave * 64) * 8),
                    16, 0, 0);
            }
        }
        __syncthreads();

#pragma unroll
        for (int kk = 0; kk < 2; ++kk) {
            short8 af[4], bfr[4];
#pragma unroll
            for (int i = 0; i < 4; ++i)
                af[i] = *(const short8*)&As[kk * 4096 + (wr * 64 + i * 16 + lr) * 32 + kq * 8];
#pragma unroll
            for (int j = 0; j < 4; ++j)
                bfr[j] = *(const short8*)&Bs[kk * 4096 + (wc * 64 + j * 16 + lr) * 32 + kq * 8];
#pragma unroll
            for (int i = 0; i < 4; ++i)
#pragma unroll
                for (int j = 0; j < 4; ++j)
                    acc[i][j] = __builtin_amdgcn_mfma_f32_16x16x32_bf16(af[i], bfr[j], acc[i][j], 0, 0, 0);
        }
    }

    __syncthreads();   // safe to reuse smem as the P-tile

    // softmax per (sq-frag j, chunk h); chunk = keys [wr*64 + 32h, +32)
#pragma unroll
    for (int j = 0; j < 4; ++j) {
        int sq_l = wc * 64 + j * 16 + lr;
#pragma unroll
        for (int h = 0; h < 2; ++h) {
            float v0[4], v1[4];
            float mx = -1e30f;
#pragma unroll
            for (int r = 0; r < 4; ++r) {
                v0[r] = acc[2 * h][j][r]     * 0.125f;
                v1[r] = acc[2 * h + 1][j][r] * 0.125f;
                mx = fmaxf(mx, fmaxf(v0[r], v1[r]));
            }
            mx = fmaxf(mx, __shfl_xor(mx, 16));
            mx = fmaxf(mx, __shfl_xor(mx, 32));
            float sm = 0.f;
#pragma unroll
            for (int r = 0; r < 4; ++r) {
                v0[r] = __expf(v0[r] - mx);
                v1[r] = __expf(v1[r] - mx);
                sm += v0[r] + v1[r];
            }
            sm += __shfl_xor(sm, 16);
            sm += __shfl_xor(sm, 32);
            float inv = 1.f / sm;
            short4v p0, p1;
#pragma unroll
            for (int r = 0; r < 4; ++r) {
                p0[r] = (short)f2bf(v0[r] * inv);
                p1[r] = (short)f2bf(v1[r] * inv);
            }
            int key0 = wr * 64 + 32 * h + kq * 4;
            *(short4v*)&smem[sq_l * 136 + key0]      = p0;
            *(short4v*)&smem[sq_l * 136 + key0 + 16] = p1;
        }
    }
    __syncthreads();

    int row = tid >> 1, half = tid & 1;
    const unsigned short* src = smem + row * 136 + half * 64;
    size_t gbase = (size_t)bz * ((size_t)S_ * S_) + (size_t)(n0 + row) * 1024 + m0 + half * 64;
#pragma unroll
    for (int t = 0; t < 8; ++t) {
        short8 v = *(const short8*)(src + t * 8);
        *(short8*)(P + gbase + t * 8) = v;
    }
}

// ---------------------------------------------------------------------------
extern "C" void kernel_launch(void* const* d_in, const int* in_sizes, int n_in,
                              void* d_out, int out_size, void* d_ws, size_t ws_size,
                              hipStream_t stream) {
    const float* x     = (const float*)d_in[0];
    const float* gn_w  = (const float*)d_in[1];
    const float* gn_b  = (const float*)d_in[2];
    const float* qkv_w = (const float*)d_in[3];
    const float* qkv_b = (const float*)d_in[4];
    const float* pr_w  = (const float*)d_in[5];
    const float* pr_b  = (const float*)d_in[6];
    float* out = (float*)d_out;

    char* w = (char*)d_ws;
    __hip_bfloat16* xnT  = (__hip_bfloat16*)w;                     // 16 MiB [16][1024][512]
    __hip_bfloat16* u    = (__hip_bfloat16*)(w + (16u << 20));     // 16 MiB [16][1024][512]
    __hip_bfloat16* Vp   = (__hip_bfloat16*)(w + (32u << 20));     // 16 MiB [16][512][1024]
    __hip_bfloat16* P    = (__hip_bfloat16*)(w + (48u << 20));     // 32 MiB [16][1024][1024]
    unsigned short* bufX = (unsigned short*)(w + (80u << 20));     // 1 MiB [WkT | wp_bf]
    unsigned short* bufY = (unsigned short*)(w + (81u << 20));     // 1 MiB [WqT | WvT]
    unsigned short* bufZ = (unsigned short*)(w + (82u << 20));     // 1 MiB [MT | W']
    float*          bqWk = (float*)(w + (83u << 20));              // 2 KiB
    float*          bvp  = (float*)(w + (83u << 20) + 4096);       // 2 KiB

    // 1) prep: transposes -> bf16, wp convert, bias matvecs
    prep_kernel<<<258, 256, 0, stream>>>(qkv_w, pr_w, qkv_b, bufX, bufY, bqWk, bvp);

    // 2) fused GroupNorm -> xnT
    gn_fused_kernel<<<B_ * NGRP, 256, 0, stream>>>(x, gn_w, gn_b, xnT);

    // 3) MT = WkT . WqT^T  (z=0)  and  W' = Wp . WvT^T  (z=1): 512x512x512 NT
    mfma_gemm<0, true, false, false, 512><<<dim3(4, 4, 2), 256, 0, stream>>>(
        bufX, bufY, nullptr, nullptr, bufZ,
        512, 512, 512, 262144, 262144, 262144, 0, 1.f, 0, 0);

    // 4) u = xnT . MT^T + bqWk[n]   M=16384, N=512, K=512
    mfma_gemm<2, true, false, false, 512><<<dim3(4, 128, 1), 256, 0, stream>>>(
        (const unsigned short*)xnT, bufZ, bqWk, nullptr, u,
        512, 512, 512, 0, 0, 0, 0, 1.f, 0, 0);

    // 5) V' = W' . xnT^T + bvp[m]   batched: M=512(c), N=1024(key), K=512
    mfma_gemm<1, true, false, true, 512><<<512, 256, 0, stream>>>(
        bufZ + 262144, (const unsigned short*)xnT, bvp, nullptr, Vp,
        512, 512, 1024, 0, (size_t)S_ * 512, (size_t)512 * S_, 0, 1.f, 5, 3);

    // 6) scores^T + fused softmax + transpose -> P[sq][key]
    scores_softmax_kernel<<<1024, 256, 0, stream>>>(
        (const unsigned short*)xnT, (const unsigned short*)u, (unsigned short*)P);

    // 7) out = V' . P^T + pr_b[m] + x   batched: M=512(c), N=1024(sq), K=1024
    mfma_gemm<1, false, true, true, 1024><<<512, 256, 0, stream>>>(
        (const unsigned short*)Vp, (const unsigned short*)P, pr_b, x, out,
        1024, 1024, 1024, (size_t)512 * S_, (size_t)S_ * S_, (size_t)512 * S_,
        (size_t)512 * S_, 1.f, 5, 3);
}

// Round 6
// 219.511 us; speedup vs baseline: 1.2131x; 1.2131x over previous
//
#include <hip/hip_runtime.h>
#include <hip/hip_bf16.h>

#define B_    16
#define C_    512
#define S_    1024      // H*W
#define NGRP  32
#define CPG   16

typedef __attribute__((ext_vector_type(8))) short  short8;
typedef __attribute__((ext_vector_type(4))) short  short4v;
typedef __attribute__((ext_vector_type(4))) float  floatx4;

__device__ __forceinline__ unsigned short f2bf(float f) {
    __hip_bfloat16 h = __float2bfloat16(f);
    unsigned short u;
    __builtin_memcpy(&u, &h, 2);
    return u;
}

// ---------------------------------------------------------------------------
// Fused GroupNorm (+transpose to xnT[b][s][c] bf16), single pass over x.
// ---------------------------------------------------------------------------
__global__ __launch_bounds__(256)
void gn_fused_kernel(const float* __restrict__ x, const float* __restrict__ w,
                     const float* __restrict__ bias, __hip_bfloat16* __restrict__ xnT) {
    int bg = blockIdx.x;
    int b = bg >> 5, g = bg & 31;
    const float4* xp = (const float4*)(x + (size_t)bg * (CPG * S_));
    int tid = threadIdx.x;

    float4 vv[16];
    float s = 0.f, ss = 0.f;
#pragma unroll
    for (int r = 0; r < 16; ++r) {
        float4 v = xp[r * 256 + tid];
        vv[r] = v;
        s  += v.x + v.y + v.z + v.w;
        ss += v.x*v.x + v.y*v.y + v.z*v.z + v.w*v.w;
    }
    for (int off = 32; off > 0; off >>= 1) {
        s  += __shfl_down(s, off);
        ss += __shfl_down(ss, off);
    }
    __shared__ float red[2][4];
    __shared__ float msh[2];
    int wid = tid >> 6, lane = tid & 63;
    if (lane == 0) { red[0][wid] = s; red[1][wid] = ss; }
    __syncthreads();
    if (tid == 0) {
        float a = 0.f, c = 0.f;
        for (int i = 0; i < 4; ++i) { a += red[0][i]; c += red[1][i]; }
        float mean = a / (float)(CPG * S_);
        float var  = c / (float)(CPG * S_) - mean * mean;
        msh[0] = mean;
        msh[1] = rsqrtf(var + 1e-5f);
    }
    __syncthreads();
    float mean = msh[0], inv = msh[1];

    float sc[16], sh[16];
#pragma unroll
    for (int c = 0; c < 16; ++c) {
        float wc = w[g * 16 + c];
        sc[c] = inv * wc;
        sh[c] = bias[g * 16 + c] - mean * inv * wc;
    }

#pragma unroll
    for (int kk = 0; kk < 4; ++kk) {
        unsigned short outp[16];
#pragma unroll
        for (int c = 0; c < 16; ++c) {
            float v = (kk == 0) ? vv[c].x : (kk == 1) ? vv[c].y : (kk == 2) ? vv[c].z : vv[c].w;
            outp[c] = f2bf(v * sc[c] + sh[c]);
        }
        int srow = 4 * tid + kk;
        unsigned short* dst = (unsigned short*)xnT + ((size_t)(b * S_ + srow) * C_ + g * 16);
        *(short8*)dst       = *(short8*)outp;
        *(short8*)(dst + 8) = *(short8*)(outp + 8);
    }
}

// ---------------------------------------------------------------------------
// Prep: weight transposes->bf16, wp convert, parallel bias matvecs.
// blocks 0..191:   64x64 transpose tiles (mat0: WkT<-Wk, mat1: WqT<-Wq, mat2: WvT<-Wv)
// blocks 192..255: wp fp32->bf16
// blocks 256..263: bqWk[j] += sum_{o in chunk} qkv_b[o]*Wk[o][j]  (coalesced + atomic)
// blocks 264..391: bvp[c] = proj_w[c][:] . qkv_b[1024:1536]       (one wave per c)
// ---------------------------------------------------------------------------
__global__ __launch_bounds__(256)
void prep_kernel(const float* __restrict__ qkv_w, const float* __restrict__ proj_w,
                 const float* __restrict__ qkv_b,
                 unsigned short* __restrict__ bufX,   // [WkT | wp_bf]
                 unsigned short* __restrict__ bufY,   // [WqT | WvT]
                 float* __restrict__ bqWk, float* __restrict__ biasvp)
{
    int blk = blockIdx.x;
    int tid = threadIdx.x;
    if (blk < 192) {
        __shared__ float T[64][65];
        int mat = blk >> 6, tile = blk & 63;
        int r0 = (tile >> 3) * 64, c0 = (tile & 7) * 64;  // dst[r0+i][c0+j] = src[c0+j][r0+i]
        const float* src; unsigned short* dst;
        if (mat == 0)      { src = qkv_w + 512 * 512;  dst = bufX; }
        else if (mat == 1) { src = qkv_w;              dst = bufY; }
        else               { src = qkv_w + 1024 * 512; dst = bufY + 262144; }
#pragma unroll
        for (int rr = 0; rr < 4; ++rr) {
            int sr = rr * 16 + (tid >> 4);
            int sc = (tid & 15) * 4;
            float4 v = *(const float4*)(src + (size_t)(c0 + sr) * 512 + r0 + sc);
            T[sc][sr] = v.x; T[sc + 1][sr] = v.y; T[sc + 2][sr] = v.z; T[sc + 3][sr] = v.w;
        }
        __syncthreads();
#pragma unroll
        for (int rr = 0; rr < 4; ++rr) {
            int dr = rr * 16 + (tid >> 4);
            int dc = (tid & 15) * 4;
            short4v o;
            o[0] = (short)f2bf(T[dr][dc]);     o[1] = (short)f2bf(T[dr][dc + 1]);
            o[2] = (short)f2bf(T[dr][dc + 2]); o[3] = (short)f2bf(T[dr][dc + 3]);
            *(short4v*)(dst + (size_t)(r0 + dr) * 512 + c0 + dc) = o;
        }
    } else if (blk < 256) {
        unsigned short* wp = bufX + 262144;
#pragma unroll
        for (int t = 0; t < 4; ++t) {
            int i = (blk - 192) * 4096 + t * 1024 + tid * 4;
            float4 v = *(const float4*)(proj_w + i);
            short4v o;
            o[0] = (short)f2bf(v.x); o[1] = (short)f2bf(v.y);
            o[2] = (short)f2bf(v.z); o[3] = (short)f2bf(v.w);
            *(short4v*)(wp + i) = o;
        }
    } else if (blk < 264) {
        // bqWk: j-range 256 (blk&1), o-chunk 128 ((blk>>1)&3); coalesced in j
        int sub = blk - 256;
        int j = (sub & 1) * 256 + tid;
        int o0 = (sub >> 1) * 128;
        float acc = 0.f;
#pragma unroll 8
        for (int oo = 0; oo < 128; ++oo) {
            int o = o0 + oo;
            acc += qkv_b[o] * qkv_w[(size_t)(512 + o) * 512 + j];
        }
        atomicAdd(&bqWk[j], acc);
    } else {
        // bvp: one wave per output channel c (contiguous row dot)
        int wv = tid >> 6, lane = tid & 63;
        int c = (blk - 264) * 4 + wv;
        float s = 0.f;
#pragma unroll
        for (int t = 0; t < 8; ++t)
            s += proj_w[(size_t)c * 512 + t * 64 + lane] * qkv_b[1024 + t * 64 + lane];
        for (int off = 32; off > 0; off >>= 1) s += __shfl_down(s, off);
        if (lane == 0) biasvp[c] = s;
    }
}

// ---------------------------------------------------------------------------
// Uniform NT bf16 MFMA GEMM, BK=64. C[m][n] = alpha*sum A[m][k]B[n][k].
// BIAS_MODE: 0 none, 1 bias[m], 2 bias[n]. KTOT compile-time for full unroll.
// ---------------------------------------------------------------------------
template<int BIAS_MODE, bool OUT_BF16, bool RESID, bool SWIZ, int KTOT>
__global__ __launch_bounds__(256)
void mfma_gemm(const unsigned short* __restrict__ A, const unsigned short* __restrict__ Bm,
               const float* __restrict__ bias, const float* __restrict__ resid,
               void* __restrict__ Yv,
               int lda, int ldb, int ldy,
               size_t sA, size_t sB, size_t sY, size_t sR, float alpha,
               int ntsh, int nxsh)
{
    __shared__ unsigned short As[2 * 128 * 32];
    __shared__ unsigned short Bs[2 * 128 * 32];
    int bx, by, bz;
    if (SWIZ) {
        int lin = blockIdx.x;
        int xcd = lin & 7, sup = lin >> 3;
        bz = xcd + ((sup >> ntsh) << 3);
        int tile = sup & ((1 << ntsh) - 1);
        bx = tile & ((1 << nxsh) - 1);
        by = tile >> nxsh;
    } else { bx = blockIdx.x; by = blockIdx.y; bz = blockIdx.z; }

    const unsigned short* Ab = A  + (size_t)bz * sA;
    const unsigned short* Bb = Bm + (size_t)bz * sB;
    const int tid = threadIdx.x, wave = tid >> 6, lane = tid & 63;
    const int m0 = by * 128, n0 = bx * 128;
    const int wr = wave >> 1, wc = wave & 1, lr = lane & 15, kq = lane >> 4;
    const int row0 = tid >> 2, kc0 = (tid & 3) << 3;

    floatx4 acc[4][4] = {};

    for (int k0 = 0; k0 < KTOT; k0 += 64) {
        __syncthreads();
#pragma unroll
        for (int kk = 0; kk < 2; ++kk) {
#pragma unroll
            for (int r = 0; r < 2; ++r) {
                const unsigned short* ga = Ab + (size_t)(m0 + r * 64 + row0) * lda + k0 + kk * 32 + kc0;
                __builtin_amdgcn_global_load_lds(
                    (const __attribute__((address_space(1))) void*)ga,
                    (__attribute__((address_space(3))) void*)(As + kk * 4096 + (r * 256 + wave * 64) * 8),
                    16, 0, 0);
                const unsigned short* gb = Bb + (size_t)(n0 + r * 64 + row0) * ldb + k0 + kk * 32 + kc0;
                __builtin_amdgcn_global_load_lds(
                    (const __attribute__((address_space(1))) void*)gb,
                    (__attribute__((address_space(3))) void*)(Bs + kk * 4096 + (r * 256 + wave * 64) * 8),
                    16, 0, 0);
            }
        }
        __syncthreads();

#pragma unroll
        for (int kk = 0; kk < 2; ++kk) {
            short8 af[4], bfr[4];
#pragma unroll
            for (int i = 0; i < 4; ++i)
                af[i] = *(const short8*)&As[kk * 4096 + (wr * 64 + i * 16 + lr) * 32 + kq * 8];
#pragma unroll
            for (int j = 0; j < 4; ++j)
                bfr[j] = *(const short8*)&Bs[kk * 4096 + (wc * 64 + j * 16 + lr) * 32 + kq * 8];
#pragma unroll
            for (int i = 0; i < 4; ++i)
#pragma unroll
                for (int j = 0; j < 4; ++j)
                    acc[i][j] = __builtin_amdgcn_mfma_f32_16x16x32_bf16(af[i], bfr[j], acc[i][j], 0, 0, 0);
        }
    }

    const size_t ybase = (size_t)bz * sY;
    const size_t rbase = (size_t)bz * sR;
#pragma unroll
    for (int i = 0; i < 4; ++i) {
#pragma unroll
        for (int r = 0; r < 4; ++r) {
            int m = m0 + wr * 64 + i * 16 + kq * 4 + r;
            float bm = (BIAS_MODE == 1) ? bias[m] : 0.f;
#pragma unroll
            for (int j = 0; j < 4; ++j) {
                int n = n0 + wc * 64 + j * 16 + lr;
                float vv = acc[i][j][r] * alpha + bm;
                if (BIAS_MODE == 2) vv += bias[n];
                if (RESID) vv += resid[rbase + (size_t)m * ldy + n];
                if (OUT_BF16)
                    ((__hip_bfloat16*)Yv)[ybase + (size_t)m * ldy + n] = __float2bfloat16(vv);
                else
                    ((float*)Yv)[ybase + (size_t)m * ldy + n] = vv;
            }
        }
    }
}

// ---------------------------------------------------------------------------
// Scores^T GEMM (BK=64) + fused 32-key-chunk softmax + LDS transpose.
// S^T[key][sq] = sum_c xnT[key][c] * u[sq][c]; sq-only logit terms cancel in
// the 32-chunk softmax. P written [sq][key] via padded-LDS transpose.
// XCD-swizzled 1-D grid (1024 blocks).
// ---------------------------------------------------------------------------
__global__ __launch_bounds__(256)
void scores_softmax_kernel(const unsigned short* __restrict__ A,   // xnT (keys)
                           const unsigned short* __restrict__ Bm,  // u (queries)
                           unsigned short* __restrict__ P)
{
    __shared__ unsigned short smem[128 * 136];   // 34816 B; staging then P-tile
    unsigned short* As = smem;                    // 2*128*32 = 8192
    unsigned short* Bs = smem + 8192;

    int lin = blockIdx.x;
    int xcd = lin & 7, sup = lin >> 3;
    int bz = xcd + ((sup >> 6) << 3);
    int tile = sup & 63;
    int bx = tile & 7, by = tile >> 3;

    const size_t sAB = (size_t)S_ * 512;
    const unsigned short* Ab = A  + (size_t)bz * sAB;
    const unsigned short* Bb = Bm + (size_t)bz * sAB;
    const int tid = threadIdx.x, wave = tid >> 6, lane = tid & 63;
    const int m0 = by * 128, n0 = bx * 128;     // m = key, n = sq
    const int wr = wave >> 1, wc = wave & 1, lr = lane & 15, kq = lane >> 4;
    const int row0 = tid >> 2, kc0 = (tid & 3) << 3;

    floatx4 acc[4][4] = {};

    for (int k0 = 0; k0 < 512; k0 += 64) {
        __syncthreads();
#pragma unroll
        for (int kk = 0; kk < 2; ++kk) {
#pragma unroll
            for (int r = 0; r < 2; ++r) {
                const unsigned short* ga = Ab + (size_t)(m0 + r * 64 + row0) * 512 + k0 + kk * 32 + kc0;
                __builtin_amdgcn_global_load_lds(
                    (const __attribute__((address_space(1))) void*)ga,
                    (__attribute__((address_space(3))) void*)(As + kk * 4096 + (r * 256 + wave * 64) * 8),
                    16, 0, 0);
                const unsigned short* gb = Bb + (size_t)(n0 + r * 64 + row0) * 512 + k0 + kk * 32 + kc0;
                __builtin_amdgcn_global_load_lds(
                    (const __attribute__((address_space(1))) void*)gb,
                    (__attribute__((address_space(3))) void*)(Bs + kk * 4096 + (r * 256 + wave * 64) * 8),
                    16, 0, 0);
            }
        }
        __syncthreads();

#pragma unroll
        for (int kk = 0; kk < 2; ++kk) {
            short8 af[4], bfr[4];
#pragma unroll
            for (int i = 0; i < 4; ++i)
                af[i] = *(const short8*)&As[kk * 4096 + (wr * 64 + i * 16 + lr) * 32 + kq * 8];
#pragma unroll
            for (int j = 0; j < 4; ++j)
                bfr[j] = *(const short8*)&Bs[kk * 4096 + (wc * 64 + j * 16 + lr) * 32 + kq * 8];
#pragma unroll
            for (int i = 0; i < 4; ++i)
#pragma unroll
                for (int j = 0; j < 4; ++j)
                    acc[i][j] = __builtin_amdgcn_mfma_f32_16x16x32_bf16(af[i], bfr[j], acc[i][j], 0, 0, 0);
        }
    }

    __syncthreads();   // safe to reuse smem as the P-tile

#pragma unroll
    for (int j = 0; j < 4; ++j) {
        int sq_l = wc * 64 + j * 16 + lr;
#pragma unroll
        for (int h = 0; h < 2; ++h) {
            float v0[4], v1[4];
            float mx = -1e30f;
#pragma unroll
            for (int r = 0; r < 4; ++r) {
                v0[r] = acc[2 * h][j][r]     * 0.125f;
                v1[r] = acc[2 * h + 1][j][r] * 0.125f;
                mx = fmaxf(mx, fmaxf(v0[r], v1[r]));
            }
            mx = fmaxf(mx, __shfl_xor(mx, 16));
            mx = fmaxf(mx, __shfl_xor(mx, 32));
            float sm = 0.f;
#pragma unroll
            for (int r = 0; r < 4; ++r) {
                v0[r] = __expf(v0[r] - mx);
                v1[r] = __expf(v1[r] - mx);
                sm += v0[r] + v1[r];
            }
            sm += __shfl_xor(sm, 16);
            sm += __shfl_xor(sm, 32);
            float inv = 1.f / sm;
            short4v p0, p1;
#pragma unroll
            for (int r = 0; r < 4; ++r) {
                p0[r] = (short)f2bf(v0[r] * inv);
                p1[r] = (short)f2bf(v1[r] * inv);
            }
            int key0 = wr * 64 + 32 * h + kq * 4;
            *(short4v*)&smem[sq_l * 136 + key0]      = p0;
            *(short4v*)&smem[sq_l * 136 + key0 + 16] = p1;
        }
    }
    __syncthreads();

    int row = tid >> 1, half = tid & 1;
    const unsigned short* src = smem + row * 136 + half * 64;
    size_t gbase = (size_t)bz * ((size_t)S_ * S_) + (size_t)(n0 + row) * 1024 + m0 + half * 64;
#pragma unroll
    for (int t = 0; t < 8; ++t) {
        short8 v = *(const short8*)(src + t * 8);
        *(short8*)(P + gbase + t * 8) = v;
    }
}

// ---------------------------------------------------------------------------
extern "C" void kernel_launch(void* const* d_in, const int* in_sizes, int n_in,
                              void* d_out, int out_size, void* d_ws, size_t ws_size,
                              hipStream_t stream) {
    const float* x     = (const float*)d_in[0];
    const float* gn_w  = (const float*)d_in[1];
    const float* gn_b  = (const float*)d_in[2];
    const float* qkv_w = (const float*)d_in[3];
    const float* qkv_b = (const float*)d_in[4];
    const float* pr_w  = (const float*)d_in[5];
    const float* pr_b  = (const float*)d_in[6];
    float* out = (float*)d_out;

    char* w = (char*)d_ws;
    __hip_bfloat16* xnT  = (__hip_bfloat16*)w;                     // 16 MiB [16][1024][512]
    __hip_bfloat16* u    = (__hip_bfloat16*)(w + (16u << 20));     // 16 MiB [16][1024][512]
    __hip_bfloat16* Vp   = (__hip_bfloat16*)(w + (32u << 20));     // 16 MiB [16][512][1024]
    __hip_bfloat16* P    = (__hip_bfloat16*)(w + (48u << 20));     // 32 MiB [16][1024][1024]
    unsigned short* bufX = (unsigned short*)(w + (80u << 20));     // 1 MiB [WkT | wp_bf]
    unsigned short* bufY = (unsigned short*)(w + (81u << 20));     // 1 MiB [WqT | WvT]
    unsigned short* bufZ = (unsigned short*)(w + (82u << 20));     // 1 MiB [MT | W']
    float*          bqWk = (float*)(w + (83u << 20));              // 2 KiB
    float*          bvp  = (float*)(w + (83u << 20) + 4096);       // 2 KiB

    // 0) zero the bqWk accumulator (atomics target)
    hipMemsetAsync(bqWk, 0, 512 * sizeof(float), stream);

    // 1) prep: transposes -> bf16, wp convert, parallel bias matvecs
    prep_kernel<<<392, 256, 0, stream>>>(qkv_w, pr_w, qkv_b, bufX, bufY, bqWk, bvp);

    // 2) fused GroupNorm -> xnT
    gn_fused_kernel<<<B_ * NGRP, 256, 0, stream>>>(x, gn_w, gn_b, xnT);

    // 3) MT = WkT . WqT^T  (z=0)  and  W' = Wp . WvT^T  (z=1): 512x512x512 NT
    mfma_gemm<0, true, false, false, 512><<<dim3(4, 4, 2), 256, 0, stream>>>(
        bufX, bufY, nullptr, nullptr, bufZ,
        512, 512, 512, 262144, 262144, 262144, 0, 1.f, 0, 0);

    // 4) u = xnT . MT^T + bqWk[n]   M=16384, N=512, K=512
    mfma_gemm<2, true, false, false, 512><<<dim3(4, 128, 1), 256, 0, stream>>>(
        (const unsigned short*)xnT, bufZ, bqWk, nullptr, u,
        512, 512, 512, 0, 0, 0, 0, 1.f, 0, 0);

    // 5) V' = W' . xnT^T + bvp[m]   batched: M=512(c), N=1024(key), K=512
    mfma_gemm<1, true, false, true, 512><<<512, 256, 0, stream>>>(
        bufZ + 262144, (const unsigned short*)xnT, bvp, nullptr, Vp,
        512, 512, 1024, 0, (size_t)S_ * 512, (size_t)512 * S_, 0, 1.f, 5, 3);

    // 6) scores^T + fused softmax + transpose -> P[sq][key]
    scores_softmax_kernel<<<1024, 256, 0, stream>>>(
        (const unsigned short*)xnT, (const unsigned short*)u, (unsigned short*)P);

    // 7) out = V' . P^T + pr_b[m] + x   batched: M=512(c), N=1024(sq), K=1024
    mfma_gemm<1, false, true, true, 1024><<<512, 256, 0, stream>>>(
        (const unsigned short*)Vp, (const unsigned short*)P, pr_b, x, out,
        1024, 1024, 1024, (size_t)512 * S_, (size_t)S_ * S_, (size_t)512 * S_,
        (size_t)512 * S_, 1.f, 5, 3);
}